// Round 7
// baseline (322.143 us; speedup 1.0000x reference)
//
#include <hip/hip_runtime.h>
#include <hip/hip_bf16.h>
#include <stdint.h>

// Problem dims (fixed by reference)
#define BB 8
#define NN 8192
#define DD 512
#define HH 8
#define DHD 64
#define NCH 32   // kv partial chunks (each = 256 rows = 4 tiles of 64)

typedef __attribute__((ext_vector_type(8))) short bf16x8;
typedef __attribute__((ext_vector_type(4))) float f32x4;
typedef __attribute__((ext_vector_type(4))) float f4v;

__device__ __forceinline__ unsigned short f2bf(float f) {
  union { float f; unsigned int u; } v; v.f = f;
  return (unsigned short)((v.u + 0x7FFFu + ((v.u >> 16) & 1u)) >> 16);
}

// packed f32x2 -> bf16x2 (RNE), single VALU instruction on gfx950.
// dst[15:0] = bf16(lo), dst[31:16] = bf16(hi) — same layout as f2bf(lo)|f2bf(hi)<<16.
__device__ __forceinline__ unsigned cvtpk(float lo, float hi) {
  unsigned r;
  asm("v_cvt_pk_bf16_f32 %0, %1, %2" : "=v"(r) : "v"(lo), "v"(hi));
  return r;
}

__device__ __forceinline__ void async16(const void* g, void* l) {
  __builtin_amdgcn_global_load_lds(
      (const __attribute__((address_space(1))) void*)g,
      (__attribute__((address_space(3))) void*)l, 16, 0, 0);
}

// ---------------- Kernel 1: fused RoPE + cast + per-head X_h^T X_h partials ----
// 1024 threads (16 waves = 4/SIMD); LDS double-buffered transposed tile.
// THIS ROUND: bf16 conversion via v_cvt_pk_bf16_f32 (1 instr / 2 floats) instead
// of manual round+shift+or (~4 instr / float) — rope-phase VALU roughly halves.
__global__ __launch_bounds__(1024, 4) void ropekv_kernel(
    const float* __restrict__ h, const float* __restrict__ cs,
    const float* __restrict__ sn, unsigned short* __restrict__ x,
    float* __restrict__ kvp, int nbh) {
  __shared__ __align__(16) unsigned int xt32[2][512 * 34];  // 139.3 KB
  int blk = blockIdx.x;
  int chunk = blk & 31, b = blk >> 5;
  int tid = threadIdx.x;
  int wave = tid >> 6, lane = tid & 63;   // wave in [0,16)
  int rpar = lane & 1;          // row parity within pair
  int g = lane >> 1;            // col-group [0,32): 8 fp32 cols each
  int cf = g * 8;               // fp32 col base in lo half [0,256)
  int l15 = lane & 15, q = lane >> 4;
  int head = wave >> 1;         // [0,8)
  int half = wave & 1;          // output d-half of this head's 64x64 kv
  int hd = head * 64;
  size_t row0 = (size_t)b * NN + (size_t)chunk * 256;
  int n0 = chunk * 256;

  f32x4 acc[2][4];              // d = half*32 + i*16 + ..., e = j*16 + ...
#pragma unroll
  for (int i = 0; i < 2; ++i)
#pragma unroll
    for (int j = 0; j < 4; ++j) acc[i][j] = (f32x4){0.f, 0.f, 0.f, 0.f};

  // single register set: 2 row-passes x (lo,hi) halves = 8 f4v = 32 regs
  f4v ha[2][2], hb[2][2];

  auto loadt = [&](int t) {
#pragma unroll
    for (int p = 0; p < 2; ++p) {
      int r = 2 * (wave + 16 * p) + rpar;          // row within tile [0,64)
      const float* hp = h + (row0 + t * 64 + r) * DD + cf;
      ha[p][0] = __builtin_nontemporal_load((const f4v*)hp);
      ha[p][1] = __builtin_nontemporal_load((const f4v*)(hp + 4));
      hb[p][0] = __builtin_nontemporal_load((const f4v*)(hp + 256));
      hb[p][1] = __builtin_nontemporal_load((const f4v*)(hp + 260));
    }
  };

  auto ropet = [&](int t) {
    int pb = t & 1;
#pragma unroll
    for (int p = 0; p < 2; ++p) {
      int r = 2 * (wave + 16 * p) + rpar;
      int nr = n0 + t * 64 + r;
      const float* cp = cs + (size_t)nr * DD + cf;
      const float* sp = sn + (size_t)nr * DD + cf;
      f4v c0 = *(const f4v*)cp, c1 = *(const f4v*)(cp + 4);
      f4v s0 = *(const f4v*)sp, s1 = *(const f4v*)(sp + 4);
      f4v xl0 = ha[p][0] * c0 - hb[p][0] * s0;   // cols cf..cf+8
      f4v xl1 = ha[p][1] * c1 - hb[p][1] * s1;
      f4v xh0 = hb[p][0] * c0 + ha[p][0] * s0;   // cols cf+256..
      f4v xh1 = hb[p][1] * c1 + ha[p][1] * s1;
      unsigned ml[4], mh[4];
      ml[0] = cvtpk(xl0.x, xl0.y);
      ml[1] = cvtpk(xl0.z, xl0.w);
      ml[2] = cvtpk(xl1.x, xl1.y);
      ml[3] = cvtpk(xl1.z, xl1.w);
      mh[0] = cvtpk(xh0.x, xh0.y);
      mh[1] = cvtpk(xh0.z, xh0.w);
      mh[2] = cvtpk(xh1.x, xh1.y);
      mh[3] = cvtpk(xh1.z, xh1.w);
      // global x store (re-read by the gemm -> keep cached, plain stores)
      unsigned short* xp = x + (row0 + t * 64 + r) * DD + cf;
      uint4 st0; st0.x = ml[0]; st0.y = ml[1]; st0.z = ml[2]; st0.w = ml[3];
      uint4 st1; st1.x = mh[0]; st1.y = mh[1]; st1.z = mh[2]; st1.w = mh[3];
      *(uint4*)xp         = st0;
      *(uint4*)(xp + 256) = st1;
      // row-pair pack via partner exchange
      unsigned pk[8];
#pragma unroll
      for (int k = 0; k < 4; ++k) {
        unsigned mine = rpar ? mh[k] : ml[k];
        unsigned send = rpar ? ml[k] : mh[k];
        unsigned recv = (unsigned)__shfl_xor((int)send, 1, 64);
        if (!rpar) {
          pk[2 * k]     = (mine & 0xffffu) | (recv << 16);
          pk[2 * k + 1] = (mine >> 16) | (recv & 0xffff0000u);
        } else {
          pk[2 * k]     = (recv & 0xffffu) | (mine << 16);
          pk[2 * k + 1] = (recv >> 16) | (mine & 0xffff0000u);
        }
      }
      int np = wave + 16 * p;                 // row-pair index within tile [0,32)
      int dbase = cf + (rpar ? 256 : 0);
      int rot = (g >> 1) & 7;                 // lane-rotated write order
#pragma unroll
      for (int w = 0; w < 8; ++w) {
        int jj = (w + rot) & 7;
        xt32[pb][(dbase + jj) * 34 + np] = pk[jj];
      }
    }
  };

  auto mfmat = [&](int t) {
    const unsigned short* xt16 = (const unsigned short*)xt32[t & 1];
#pragma unroll
    for (int ks = 0; ks < 64; ks += 32) {
      bf16x8 af[2], bf[4];
#pragma unroll
      for (int i = 0; i < 2; ++i)
        af[i] = *(const bf16x8*)&xt16[(hd + half * 32 + i * 16 + l15) * 68 + ks + q * 8];
#pragma unroll
      for (int j = 0; j < 4; ++j)
        bf[j] = *(const bf16x8*)&xt16[(hd + j * 16 + l15) * 68 + ks + q * 8];
#pragma unroll
      for (int i = 0; i < 2; ++i)
#pragma unroll
        for (int j = 0; j < 4; ++j)
          acc[i][j] = __builtin_amdgcn_mfma_f32_16x16x32_bf16(af[i], bf[j], acc[i][j], 0, 0, 0);
    }
  };

  // prologue: tile0 roped into buf0, tile1 loads in flight
  loadt(0);
  ropet(0);
  loadt(1);
  __syncthreads();                 // buf0 ready
#pragma unroll
  for (int t = 0; t < 4; ++t) {
    if (t < 3) ropet(t + 1);       // consume loads(t+1) -> buf (t+1)&1 + x
    if (t < 2) loadt(t + 2);       // refill regs for next phase
    mfmat(t);                      // MFMA on buf t&1 (overlaps rope/load above)
    __syncthreads();               // buf (t+1)&1 ready; buf t&1 reads done
  }

  int bh = b * 8 + head;
  float* dst = kvp + ((size_t)chunk * nbh + bh) * 4096;
#pragma unroll
  for (int i = 0; i < 2; ++i)
#pragma unroll
    for (int j = 0; j < 4; ++j)
#pragma unroll
      for (int reg = 0; reg < 4; ++reg)
        dst[(half * 32 + i * 16 + q * 4 + reg) * 64 + j * 16 + l15] = acc[i][j][reg];
}

// ---------------- Kernel 2: sum kv partials once, WkvT[bh][e][f] = sum_d W[h*64+d][f]*kv[d][e]
// (unchanged)
__global__ __launch_bounds__(512, 2) void wkvt_kernel(
    const float* __restrict__ W, const float* __restrict__ kvp,
    unsigned short* __restrict__ wkvt, int nbh) {
  __shared__ float kvs[64 * 16];
  __shared__ __align__(16) float ws[64 * 512];
  int blk = blockIdx.x;
  int bh = blk >> 2, eq = blk & 3;
  int b = bh >> 3, hh = bh & 7;
  int tid = threadIdx.x;
  if (tid < 256) {
    int idx = tid * 4;
    int d = idx >> 4, ec = idx & 15;
    f4v s = (f4v){0.f, 0.f, 0.f, 0.f};
    for (int c = 0; c < NCH; ++c)
      s += *(const f4v*)&kvp[((size_t)c * nbh + bh) * 4096 + d * 64 + eq * 16 + ec];
    *(f4v*)&kvs[idx] = s;
  }
#pragma unroll
  for (int i = 0; i < 16; ++i) {
    int idx = i * 2048 + tid * 4;
    *(f4v*)&ws[idx] = *(const f4v*)&W[(size_t)(hh * DHD + (idx >> 9)) * DD + (idx & 511)];
  }
  __syncthreads();
  int el = tid & 15, fg = tid >> 4;
  f4v av[4];
#pragma unroll
  for (int k = 0; k < 4; ++k) av[k] = (f4v){0.f, 0.f, 0.f, 0.f};
#pragma unroll 8
  for (int d = 0; d < 64; ++d) {
    float kvv = kvs[d * 16 + el];
    const f4v* wr = (const f4v*)&ws[d * DD + fg * 16];
#pragma unroll
    for (int k = 0; k < 4; ++k) av[k] += wr[k] * kvv;
  }
  unsigned short tb[16];
#pragma unroll
  for (int k = 0; k < 4; ++k) {
    tb[k * 4 + 0] = f2bf(av[k].x); tb[k * 4 + 1] = f2bf(av[k].y);
    tb[k * 4 + 2] = f2bf(av[k].z); tb[k * 4 + 3] = f2bf(av[k].w);
  }
  size_t ob = ((size_t)b * DD + hh * DHD + eq * 16 + el) * DD + fg * 16;
  *(uint4*)&wkvt[ob]     = *(uint4*)&tb[0];
  *(uint4*)&wkvt[ob + 8] = *(uint4*)&tb[8];
}

// ---------------- Kernel 3: out[b] = x_b [8192x512] @ WkvT_b^T  (bf16 MFMA, fp32 out) ----
// (unchanged from round 6: 128x128 tile, 4 waves, 32 KiB LDS, 3 blocks/CU,
// grid (64,4,8) with blockIdx.x fastest so consecutive blocks share B-panel)
__global__ __launch_bounds__(256, 3) void gemm_kernel(const unsigned short* __restrict__ x,
                                                      const unsigned short* __restrict__ wkvt,
                                                      float* __restrict__ out) {
  __shared__ __align__(16) unsigned short As[128 * 64];  // [m][k] 16 KB
  __shared__ __align__(16) unsigned short Bs[128 * 64];  // [c][k] 16 KB
  int mt = blockIdx.x, ct = blockIdx.y, bz = blockIdx.z;
  int tid = threadIdx.x, wave = tid >> 6, lane = tid & 63;
  int wm = wave & 1, wn = wave >> 1;   // wave tile: rows wm*64, cols wn*64
  int l15 = lane & 15, q = lane >> 4;
  int lrow = lane >> 3, lcol = (lane & 7) * 8;
  const unsigned short* Ag = x    + ((size_t)bz * NN + mt * 128) * DD;
  const unsigned short* Bg = wkvt + ((size_t)bz * DD + ct * 128) * DD;
  f32x4 acc[4][4];
#pragma unroll
  for (int i = 0; i < 4; ++i)
#pragma unroll
    for (int j = 0; j < 4; ++j) acc[i][j] = (f32x4){0.f, 0.f, 0.f, 0.f};

  for (int kk = 0; kk < 512; kk += 64) {
#pragma unroll
    for (int i = 0; i < 4; ++i)
      async16(Ag + (size_t)(wave * 32 + i * 8 + lrow) * DD + kk + lcol,
              &As[(wave * 32 + i * 8) * 64]);
#pragma unroll
    for (int i = 0; i < 4; ++i)
      async16(Bg + (size_t)(wave * 32 + i * 8 + lrow) * DD + kk + lcol,
              &Bs[(wave * 32 + i * 8) * 64]);
    __syncthreads();
#pragma unroll
    for (int ks = 0; ks < 64; ks += 32) {
      bf16x8 a[4], bb[4];
#pragma unroll
      for (int i = 0; i < 4; ++i)
        a[i] = *(const bf16x8*)&As[(wm * 64 + i * 16 + l15) * 64 + ks + q * 8];
#pragma unroll
      for (int j = 0; j < 4; ++j)
        bb[j] = *(const bf16x8*)&Bs[(wn * 64 + j * 16 + l15) * 64 + ks + q * 8];
#pragma unroll
      for (int i = 0; i < 4; ++i)
#pragma unroll
        for (int j = 0; j < 4; ++j)
          acc[i][j] = __builtin_amdgcn_mfma_f32_16x16x32_bf16(a[i], bb[j], acc[i][j], 0, 0, 0);
    }
    __syncthreads();
  }
  float* ob = out + ((size_t)bz * NN + mt * 128 + wm * 64) * DD + ct * 128 + wn * 64;
#pragma unroll
  for (int i = 0; i < 4; ++i)
#pragma unroll
    for (int j = 0; j < 4; ++j) {
      int row = i * 16 + q * 4;
      int col = j * 16 + l15;
#pragma unroll
      for (int reg = 0; reg < 4; ++reg)
        __builtin_nontemporal_store(acc[i][j][reg], &ob[(size_t)(row + reg) * DD + col]);
    }
}

extern "C" void kernel_launch(void* const* d_in, const int* in_sizes, int n_in,
                              void* d_out, int out_size, void* d_ws, size_t ws_size,
                              hipStream_t stream) {
  (void)in_sizes; (void)n_in; (void)out_size;
  const float* h  = (const float*)d_in[0];
  const float* W  = (const float*)d_in[1];
  const float* cs = (const float*)d_in[2];
  const float* sn = (const float*)d_in[3];
  float* out = (float*)d_out;

  const size_t x_full     = (size_t)BB * NN * DD * 2;               // 67.1 MB
  const size_t kvp_full   = (size_t)NCH * BB * HH * DHD * DHD * 4;  // 33.6 MB
  const size_t wkvt_full  = (size_t)BB * DD * DD * 2;               // 4.2 MB
  const size_t x_batch    = (size_t)NN * DD * 2;                    // 8.4 MB
  const size_t kvp_batch  = (size_t)NCH * HH * DHD * DHD * 4;       // 4.2 MB
  const size_t wkvt_batch = (size_t)DD * DD * 2;                    // 524 KB

  if (ws_size >= x_full + kvp_full + wkvt_full) {
    // -------- full path: 3 launches --------
    unsigned short* xw   = (unsigned short*)d_ws;
    float*          kvp  = (float*)((char*)d_ws + x_full);
    unsigned short* wkvt = (unsigned short*)((char*)d_ws + x_full + kvp_full);
    ropekv_kernel<<<dim3(BB * 32), dim3(1024), 0, stream>>>(h, cs, sn, xw, kvp, BB * HH);
    wkvt_kernel<<<dim3(BB * HH * 4), dim3(512), 0, stream>>>(W, kvp, wkvt, BB * HH);
    gemm_kernel<<<dim3(NN / 128, DD / 128, BB), dim3(256), 0, stream>>>(xw, wkvt, out);
  } else {
    // -------- per-batch fallback (~13 MB workspace) --------
    unsigned short* xw   = (unsigned short*)d_ws;
    float*          kvp  = (float*)((char*)d_ws + x_batch);
    unsigned short* wkvt = (unsigned short*)((char*)d_ws + x_batch + kvp_batch);
    for (int b = 0; b < BB; ++b) {
      ropekv_kernel<<<dim3(32), dim3(1024), 0, stream>>>(
          h + (size_t)b * NN * DD, cs, sn, xw, kvp, HH);
      wkvt_kernel<<<dim3(HH * 4), dim3(512), 0, stream>>>(W, kvp, wkvt, HH);
      gemm_kernel<<<dim3(NN / 128, DD / 128, 1), dim3(256), 0, stream>>>(
          xw, wkvt, out + (size_t)b * NN * DD);
    }
  }
}

// Round 8
// 310.713 us; speedup vs baseline: 1.0368x; 1.0368x over previous
//
#include <hip/hip_runtime.h>
#include <hip/hip_bf16.h>
#include <stdint.h>

// Problem dims (fixed by reference)
#define BB 8
#define NN 8192
#define DD 512
#define HH 8
#define DHD 64
#define NCH 32   // kv partial chunks (each = 256 rows = 4 tiles of 64)

typedef __attribute__((ext_vector_type(8))) short bf16x8;
typedef __attribute__((ext_vector_type(4))) float f32x4;
typedef __attribute__((ext_vector_type(16))) float f32x16;
typedef __attribute__((ext_vector_type(4))) float f4v;

__device__ __forceinline__ unsigned short f2bf(float f) {
  union { float f; unsigned int u; } v; v.f = f;
  return (unsigned short)((v.u + 0x7FFFu + ((v.u >> 16) & 1u)) >> 16);
}

// packed f32x2 -> bf16x2 (RNE), single VALU instruction on gfx950.
__device__ __forceinline__ unsigned cvtpk(float lo, float hi) {
  unsigned r;
  asm("v_cvt_pk_bf16_f32 %0, %1, %2" : "=v"(r) : "v"(lo), "v"(hi));
  return r;
}

__device__ __forceinline__ void async16(const void* g, void* l) {
  __builtin_amdgcn_global_load_lds(
      (const __attribute__((address_space(1))) void*)g,
      (__attribute__((address_space(3))) void*)l, 16, 0, 0);
}

// ---------------- Kernel 1: fused RoPE + cast + per-head X_h^T X_h partials ----
// (unchanged from round 7 — single-variable experiment on the gemm)
__global__ __launch_bounds__(1024, 4) void ropekv_kernel(
    const float* __restrict__ h, const float* __restrict__ cs,
    const float* __restrict__ sn, unsigned short* __restrict__ x,
    float* __restrict__ kvp, int nbh) {
  __shared__ __align__(16) unsigned int xt32[2][512 * 34];  // 139.3 KB
  int blk = blockIdx.x;
  int chunk = blk & 31, b = blk >> 5;
  int tid = threadIdx.x;
  int wave = tid >> 6, lane = tid & 63;   // wave in [0,16)
  int rpar = lane & 1;          // row parity within pair
  int g = lane >> 1;            // col-group [0,32): 8 fp32 cols each
  int cf = g * 8;               // fp32 col base in lo half [0,256)
  int l15 = lane & 15, q = lane >> 4;
  int head = wave >> 1;         // [0,8)
  int half = wave & 1;          // output d-half of this head's 64x64 kv
  int hd = head * 64;
  size_t row0 = (size_t)b * NN + (size_t)chunk * 256;
  int n0 = chunk * 256;

  f32x4 acc[2][4];              // d = half*32 + i*16 + ..., e = j*16 + ...
#pragma unroll
  for (int i = 0; i < 2; ++i)
#pragma unroll
    for (int j = 0; j < 4; ++j) acc[i][j] = (f32x4){0.f, 0.f, 0.f, 0.f};

  // single register set: 2 row-passes x (lo,hi) halves = 8 f4v = 32 regs
  f4v ha[2][2], hb[2][2];

  auto loadt = [&](int t) {
#pragma unroll
    for (int p = 0; p < 2; ++p) {
      int r = 2 * (wave + 16 * p) + rpar;          // row within tile [0,64)
      const float* hp = h + (row0 + t * 64 + r) * DD + cf;
      ha[p][0] = __builtin_nontemporal_load((const f4v*)hp);
      ha[p][1] = __builtin_nontemporal_load((const f4v*)(hp + 4));
      hb[p][0] = __builtin_nontemporal_load((const f4v*)(hp + 256));
      hb[p][1] = __builtin_nontemporal_load((const f4v*)(hp + 260));
    }
  };

  auto ropet = [&](int t) {
    int pb = t & 1;
#pragma unroll
    for (int p = 0; p < 2; ++p) {
      int r = 2 * (wave + 16 * p) + rpar;
      int nr = n0 + t * 64 + r;
      const float* cp = cs + (size_t)nr * DD + cf;
      const float* sp = sn + (size_t)nr * DD + cf;
      f4v c0 = *(const f4v*)cp, c1 = *(const f4v*)(cp + 4);
      f4v s0 = *(const f4v*)sp, s1 = *(const f4v*)(sp + 4);
      f4v xl0 = ha[p][0] * c0 - hb[p][0] * s0;   // cols cf..cf+8
      f4v xl1 = ha[p][1] * c1 - hb[p][1] * s1;
      f4v xh0 = hb[p][0] * c0 + ha[p][0] * s0;   // cols cf+256..
      f4v xh1 = hb[p][1] * c1 + ha[p][1] * s1;
      unsigned ml[4], mh[4];
      ml[0] = cvtpk(xl0.x, xl0.y);
      ml[1] = cvtpk(xl0.z, xl0.w);
      ml[2] = cvtpk(xl1.x, xl1.y);
      ml[3] = cvtpk(xl1.z, xl1.w);
      mh[0] = cvtpk(xh0.x, xh0.y);
      mh[1] = cvtpk(xh0.z, xh0.w);
      mh[2] = cvtpk(xh1.x, xh1.y);
      mh[3] = cvtpk(xh1.z, xh1.w);
      // global x store (re-read by the gemm -> keep cached, plain stores)
      unsigned short* xp = x + (row0 + t * 64 + r) * DD + cf;
      uint4 st0; st0.x = ml[0]; st0.y = ml[1]; st0.z = ml[2]; st0.w = ml[3];
      uint4 st1; st1.x = mh[0]; st1.y = mh[1]; st1.z = mh[2]; st1.w = mh[3];
      *(uint4*)xp         = st0;
      *(uint4*)(xp + 256) = st1;
      // row-pair pack via partner exchange
      unsigned pk[8];
#pragma unroll
      for (int k = 0; k < 4; ++k) {
        unsigned mine = rpar ? mh[k] : ml[k];
        unsigned send = rpar ? ml[k] : mh[k];
        unsigned recv = (unsigned)__shfl_xor((int)send, 1, 64);
        if (!rpar) {
          pk[2 * k]     = (mine & 0xffffu) | (recv << 16);
          pk[2 * k + 1] = (mine >> 16) | (recv & 0xffff0000u);
        } else {
          pk[2 * k]     = (recv & 0xffffu) | (mine << 16);
          pk[2 * k + 1] = (recv >> 16) | (mine & 0xffff0000u);
        }
      }
      int np = wave + 16 * p;                 // row-pair index within tile [0,32)
      int dbase = cf + (rpar ? 256 : 0);
      int rot = (g >> 1) & 7;                 // lane-rotated write order
#pragma unroll
      for (int w = 0; w < 8; ++w) {
        int jj = (w + rot) & 7;
        xt32[pb][(dbase + jj) * 34 + np] = pk[jj];
      }
    }
  };

  auto mfmat = [&](int t) {
    const unsigned short* xt16 = (const unsigned short*)xt32[t & 1];
#pragma unroll
    for (int ks = 0; ks < 64; ks += 32) {
      bf16x8 af[2], bf[4];
#pragma unroll
      for (int i = 0; i < 2; ++i)
        af[i] = *(const bf16x8*)&xt16[(hd + half * 32 + i * 16 + l15) * 68 + ks + q * 8];
#pragma unroll
      for (int j = 0; j < 4; ++j)
        bf[j] = *(const bf16x8*)&xt16[(hd + j * 16 + l15) * 68 + ks + q * 8];
#pragma unroll
      for (int i = 0; i < 2; ++i)
#pragma unroll
        for (int j = 0; j < 4; ++j)
          acc[i][j] = __builtin_amdgcn_mfma_f32_16x16x32_bf16(af[i], bf[j], acc[i][j], 0, 0, 0);
    }
  };

  // prologue: tile0 roped into buf0, tile1 loads in flight
  loadt(0);
  ropet(0);
  loadt(1);
  __syncthreads();                 // buf0 ready
#pragma unroll
  for (int t = 0; t < 4; ++t) {
    if (t < 3) ropet(t + 1);       // consume loads(t+1) -> buf (t+1)&1 + x
    if (t < 2) loadt(t + 2);       // refill regs for next phase
    mfmat(t);                      // MFMA on buf t&1 (overlaps rope/load above)
    __syncthreads();               // buf (t+1)&1 ready; buf t&1 reads done
  }

  int bh = b * 8 + head;
  float* dst = kvp + ((size_t)chunk * nbh + bh) * 4096;
#pragma unroll
  for (int i = 0; i < 2; ++i)
#pragma unroll
    for (int j = 0; j < 4; ++j)
#pragma unroll
      for (int reg = 0; reg < 4; ++reg)
        dst[(half * 32 + i * 16 + q * 4 + reg) * 64 + j * 16 + l15] = acc[i][j][reg];
}

// ---------------- Kernel 2: sum kv partials once, WkvT[bh][e][f] = sum_d W[h*64+d][f]*kv[d][e]
// (unchanged)
__global__ __launch_bounds__(512, 2) void wkvt_kernel(
    const float* __restrict__ W, const float* __restrict__ kvp,
    unsigned short* __restrict__ wkvt, int nbh) {
  __shared__ float kvs[64 * 16];
  __shared__ __align__(16) float ws[64 * 512];
  int blk = blockIdx.x;
  int bh = blk >> 2, eq = blk & 3;
  int b = bh >> 3, hh = bh & 7;
  int tid = threadIdx.x;
  if (tid < 256) {
    int idx = tid * 4;
    int d = idx >> 4, ec = idx & 15;
    f4v s = (f4v){0.f, 0.f, 0.f, 0.f};
    for (int c = 0; c < NCH; ++c)
      s += *(const f4v*)&kvp[((size_t)c * nbh + bh) * 4096 + d * 64 + eq * 16 + ec];
    *(f4v*)&kvs[idx] = s;
  }
#pragma unroll
  for (int i = 0; i < 16; ++i) {
    int idx = i * 2048 + tid * 4;
    *(f4v*)&ws[idx] = *(const f4v*)&W[(size_t)(hh * DHD + (idx >> 9)) * DD + (idx & 511)];
  }
  __syncthreads();
  int el = tid & 15, fg = tid >> 4;
  f4v av[4];
#pragma unroll
  for (int k = 0; k < 4; ++k) av[k] = (f4v){0.f, 0.f, 0.f, 0.f};
#pragma unroll 8
  for (int d = 0; d < 64; ++d) {
    float kvv = kvs[d * 16 + el];
    const f4v* wr = (const f4v*)&ws[d * DD + fg * 16];
#pragma unroll
    for (int k = 0; k < 4; ++k) av[k] += wr[k] * kvv;
  }
  unsigned short tb[16];
#pragma unroll
  for (int k = 0; k < 4; ++k) {
    tb[k * 4 + 0] = f2bf(av[k].x); tb[k * 4 + 1] = f2bf(av[k].y);
    tb[k * 4 + 2] = f2bf(av[k].z); tb[k * 4 + 3] = f2bf(av[k].w);
  }
  size_t ob = ((size_t)b * DD + hh * DHD + eq * 16 + el) * DD + fg * 16;
  *(uint4*)&wkvt[ob]     = *(uint4*)&tb[0];
  *(uint4*)&wkvt[ob + 8] = *(uint4*)&tb[8];
}

// ---------------- Kernel 3: out[b] = x_b [8192x512] @ WkvT_b^T  (bf16 MFMA, fp32 out) ----
// THIS ROUND: same 128x128 tile + staging skeleton, but
//  (a) 32x32x16 MFMA (2x2 tiles/wave; ~17% fewer matrix-pipe cycles),
//  (b) XOR slot swizzle (R3's verified scheme) on stage-source + ds_read:
//      kills the 16-way bank conflict of the linear [128][64] tile (-> 4-way),
//  (c) acc 128->64 regs -> launch_bounds(256,4) = 4 blocks/CU (was 3).
// C/D mapping (HW-verified m74/m101): col=lane&31, row=(reg&3)+8*(reg>>2)+4*(lane>>5).
__global__ __launch_bounds__(256, 4) void gemm_kernel(const unsigned short* __restrict__ x,
                                                      const unsigned short* __restrict__ wkvt,
                                                      float* __restrict__ out) {
  __shared__ __align__(16) unsigned short As[128 * 64];  // 16 KB, slot-swizzled
  __shared__ __align__(16) unsigned short Bs[128 * 64];  // 16 KB
  int mt = blockIdx.x, ct = blockIdx.y, bz = blockIdx.z;
  int tid = threadIdx.x, wave = tid >> 6, lane = tid & 63;
  int wm = wave & 1, wn = wave >> 1;   // wave tile: rows wm*64, cols wn*64
  int l31 = lane & 31, hk = lane >> 5; // MFMA row-in-tile, k-half
  const unsigned short* Ag = x    + ((size_t)bz * NN + mt * 128) * DD;
  const unsigned short* Bg = wkvt + ((size_t)bz * DD + ct * 128) * DD;

  // staging: 1024 16B-units per matrix, 4 per thread; unit u -> LDS linear u*16B,
  // source slot pre-swizzled ss = (u&7)^(row&7) so reads can unswizzle.
  int su_row[4], su_ss[4];
#pragma unroll
  for (int i = 0; i < 4; ++i) {
    int u = i * 256 + tid;
    su_row[i] = u >> 3;
    su_ss[i]  = (u & 7) ^ ((u >> 3) & 7);
  }

  f32x16 acc[2][2];
#pragma unroll
  for (int mi = 0; mi < 2; ++mi)
#pragma unroll
    for (int ni = 0; ni < 2; ++ni)
#pragma unroll
      for (int r = 0; r < 16; ++r) acc[mi][ni][r] = 0.f;

  for (int kk = 0; kk < 512; kk += 64) {
#pragma unroll
    for (int i = 0; i < 4; ++i) {
      int u = i * 256 + tid;
      async16(Ag + (size_t)su_row[i] * DD + kk + su_ss[i] * 8, &As[u * 8]);
      async16(Bg + (size_t)su_row[i] * DD + kk + su_ss[i] * 8, &Bs[u * 8]);
    }
    __syncthreads();
#pragma unroll
    for (int ks = 0; ks < 64; ks += 16) {
      bf16x8 a[2], bb[2];
#pragma unroll
      for (int mi = 0; mi < 2; ++mi) {
        int row = wm * 64 + mi * 32 + l31;
        int s = ((ks >> 3) + hk) ^ (row & 7);
        a[mi] = *(const bf16x8*)&As[row * 64 + s * 8];
      }
#pragma unroll
      for (int ni = 0; ni < 2; ++ni) {
        int row = wn * 64 + ni * 32 + l31;
        int s = ((ks >> 3) + hk) ^ (row & 7);
        bb[ni] = *(const bf16x8*)&Bs[row * 64 + s * 8];
      }
#pragma unroll
      for (int mi = 0; mi < 2; ++mi)
#pragma unroll
        for (int ni = 0; ni < 2; ++ni)
          acc[mi][ni] = __builtin_amdgcn_mfma_f32_32x32x16_bf16(a[mi], bb[ni], acc[mi][ni], 0, 0, 0);
    }
    __syncthreads();
  }
  float* ob = out + ((size_t)bz * NN + mt * 128) * DD + ct * 128;
#pragma unroll
  for (int mi = 0; mi < 2; ++mi)
#pragma unroll
    for (int ni = 0; ni < 2; ++ni)
#pragma unroll
      for (int r = 0; r < 16; ++r) {
        int row = wm * 64 + mi * 32 + (r & 3) + 8 * (r >> 2) + 4 * hk;
        int col = wn * 64 + ni * 32 + l31;
        __builtin_nontemporal_store(acc[mi][ni][r], &ob[(size_t)row * DD + col]);
      }
}

extern "C" void kernel_launch(void* const* d_in, const int* in_sizes, int n_in,
                              void* d_out, int out_size, void* d_ws, size_t ws_size,
                              hipStream_t stream) {
  (void)in_sizes; (void)n_in; (void)out_size;
  const float* h  = (const float*)d_in[0];
  const float* W  = (const float*)d_in[1];
  const float* cs = (const float*)d_in[2];
  const float* sn = (const float*)d_in[3];
  float* out = (float*)d_out;

  const size_t x_full     = (size_t)BB * NN * DD * 2;               // 67.1 MB
  const size_t kvp_full   = (size_t)NCH * BB * HH * DHD * DHD * 4;  // 33.6 MB
  const size_t wkvt_full  = (size_t)BB * DD * DD * 2;               // 4.2 MB
  const size_t x_batch    = (size_t)NN * DD * 2;                    // 8.4 MB
  const size_t kvp_batch  = (size_t)NCH * HH * DHD * DHD * 4;       // 4.2 MB
  const size_t wkvt_batch = (size_t)DD * DD * 2;                    // 524 KB

  if (ws_size >= x_full + kvp_full + wkvt_full) {
    // -------- full path: 3 launches --------
    unsigned short* xw   = (unsigned short*)d_ws;
    float*          kvp  = (float*)((char*)d_ws + x_full);
    unsigned short* wkvt = (unsigned short*)((char*)d_ws + x_full + kvp_full);
    ropekv_kernel<<<dim3(BB * 32), dim3(1024), 0, stream>>>(h, cs, sn, xw, kvp, BB * HH);
    wkvt_kernel<<<dim3(BB * HH * 4), dim3(512), 0, stream>>>(W, kvp, wkvt, BB * HH);
    gemm_kernel<<<dim3(NN / 128, DD / 128, BB), dim3(256), 0, stream>>>(xw, wkvt, out);
  } else {
    // -------- per-batch fallback (~13 MB workspace) --------
    unsigned short* xw   = (unsigned short*)d_ws;
    float*          kvp  = (float*)((char*)d_ws + x_batch);
    unsigned short* wkvt = (unsigned short*)((char*)d_ws + x_batch + kvp_batch);
    for (int b = 0; b < BB; ++b) {
      ropekv_kernel<<<dim3(32), dim3(1024), 0, stream>>>(
          h + (size_t)b * NN * DD, cs, sn, xw, kvp, HH);
      wkvt_kernel<<<dim3(HH * 4), dim3(512), 0, stream>>>(W, kvp, wkvt, HH);
      gemm_kernel<<<dim3(NN / 128, DD / 128, 1), dim3(256), 0, stream>>>(
          xw, wkvt, out + (size_t)b * NN * DD);
    }
  }
}